// Round 1
// baseline (25021.310 us; speedup 1.0000x reference)
//
#include <hip/hip_runtime.h>

// LSTM: B=256, T=512, F=512, H=512. W [1024, 2048] (gates i,j,f,o), b [2048].
// out [B,T,H] fp32.
//
// Split: gates = x_t @ Wx  (time-parallel, precomputed as XW)  +  h_t @ Wh (sequential).
// All matmuls in fp16 MFMA (16x16x32) with fp32 accumulate; cell math fp32.
//
// Recurrent kernel: 16 groups x 16 slices = 256 wgs (1/CU, 158KB LDS forces
// full residency -> intra-group spin barriers are safe). Each wg owns 16 batch
// rows x 32 hidden units; Wh slice lives in LDS for the whole kernel.

typedef _Float16 f16;
typedef _Float16 f16x8 __attribute__((ext_vector_type(8)));
typedef float f32x4 __attribute__((ext_vector_type(4)));

#define B_ 256
#define T_ 512
#define F_ 512
#define H_ 512
#define GG 16     // groups (batch)
#define SS 16     // wgs per group (hidden slices)
#define MG 16     // batch rows per group

__device__ __forceinline__ float sigf(float x) { return 1.0f / (1.0f + __expf(-x)); }
__device__ __forceinline__ float tanh_(float x) { return 1.0f - 2.0f / (__expf(2.0f * x) + 1.0f); }

// ---- prep: W [1024][2048] fp32 -> WT [2048][1024] fp16 (WT[n][k] = W[k][n]) ----
__global__ void prep_w(const float* __restrict__ W, f16* __restrict__ WT) {
    int k = blockIdx.x;          // 0..1023
    int tid = threadIdx.x;       // 0..255
    #pragma unroll
    for (int it = 0; it < 8; ++it) {
        int n = it * 256 + tid;
        WT[(size_t)n * 1024 + k] = (f16)W[(size_t)k * 2048 + n];
    }
}

// ---- prep: x [B][T][F] fp32 -> x16 [t_local][b][k] fp16 for one T-chunk ----
__global__ void prep_x(const float* __restrict__ x, f16* __restrict__ x16, int t0) {
    int b = blockIdx.x;          // 0..255
    int t = blockIdx.y;          // 0..TC-1
    int tid = threadIdx.x;       // 0..63
    const float4* src = (const float4*)(x + ((size_t)b * T_ + t0 + t) * F_) + tid * 2;
    float4 v0 = src[0], v1 = src[1];
    union { f16 h[8]; uint4 u; } pk;
    pk.h[0] = (f16)v0.x; pk.h[1] = (f16)v0.y; pk.h[2] = (f16)v0.z; pk.h[3] = (f16)v0.w;
    pk.h[4] = (f16)v1.x; pk.h[5] = (f16)v1.y; pk.h[6] = (f16)v1.z; pk.h[7] = (f16)v1.w;
    *(uint4*)(x16 + ((size_t)t * 256 + b) * 512 + tid * 8) = pk.u;
}

// ---- XW = x16 @ Wx : M = TC*256 (row m = t*256+b), N = 2048, K = 512 ----
// 128x128 tile, BK=32, 4 waves (2x2 quadrants of 64x64). XW stored fp16 [m][n].
__global__ __launch_bounds__(256, 2) void xw_gemm(const f16* __restrict__ x16,
                                                  const f16* __restrict__ WT,
                                                  f16* __restrict__ XW) {
    __shared__ f16 Al[128 * 40];   // [row][k] pad 40 -> 2-way banks on b128 reads
    __shared__ f16 Bl[128 * 40];   // [col][k]
    const int nt = blockIdx.x, mt = blockIdx.y;   // n-tile fastest: A-panel L2 reuse
    const int tid = threadIdx.x;
    const int w = tid >> 6, l = tid & 63;
    const int l15 = l & 15, l4 = l >> 4;
    const int wr = w >> 1, wc = w & 1;
    const int n0 = nt * 128;
    const size_t arow = (size_t)mt * 128;         // m-rows [arow, arow+128)

    f32x4 acc[4][4] = {};
    const int r = tid >> 1, hf = tid & 1;
    for (int kk = 0; kk < 16; ++kk) {
        const int k0 = kk * 32;
        {   // stage A: 128 rows x 32 k  (2 threads/row, 16 halfs each)
            const uint4* sa = (const uint4*)(x16 + (arow + r) * 512 + k0 + hf * 16);
            uint4 a0 = sa[0], a1 = sa[1];
            *(uint4*)&Al[r * 40 + hf * 16] = a0;
            *(uint4*)&Al[r * 40 + hf * 16 + 8] = a1;
            // stage B: cols n0..n0+127 x 32 k from WT[n][k]
            const uint4* sb = (const uint4*)(WT + (size_t)(n0 + r) * 1024 + k0 + hf * 16);
            uint4 b0 = sb[0], b1 = sb[1];
            *(uint4*)&Bl[r * 40 + hf * 16] = b0;
            *(uint4*)&Bl[r * 40 + hf * 16 + 8] = b1;
        }
        __syncthreads();
        #pragma unroll
        for (int i = 0; i < 4; ++i) {
            f16x8 af = *(const f16x8*)&Al[(wr * 64 + i * 16 + l15) * 40 + l4 * 8];
            #pragma unroll
            for (int j = 0; j < 4; ++j) {
                f16x8 bf = *(const f16x8*)&Bl[(wc * 64 + j * 16 + l15) * 40 + l4 * 8];
                acc[i][j] = __builtin_amdgcn_mfma_f32_16x16x32_f16(af, bf, acc[i][j], 0, 0, 0);
            }
        }
        __syncthreads();
    }
    // epilogue: D lane map col=l&15, row=(l>>4)*4+rr
    #pragma unroll
    for (int i = 0; i < 4; ++i) {
        #pragma unroll
        for (int rr = 0; rr < 4; ++rr) {
            size_t m = arow + wr * 64 + i * 16 + l4 * 4 + rr;
            f16* dst = XW + m * 2048 + n0 + wc * 64 + l15;
            #pragma unroll
            for (int j = 0; j < 4; ++j) dst[j * 16] = (f16)acc[i][j][rr];
        }
    }
}

// ---- persistent recurrent kernel for one T-chunk ----
__global__ __launch_bounds__(256, 1) void rnn_chunk(
    const f16* __restrict__ XW, const f16* __restrict__ WT,
    const float* __restrict__ bias, f16* __restrict__ hbuf,
    float* __restrict__ cbuf, int* __restrict__ arr,
    float* __restrict__ out, int t0, int TC) {
    __shared__ f16 WhT[128 * 520];   // [gatecol 0..127][k 0..511], pad 520
    __shared__ f16 hld[16 * 520];    // [row][k]
    __shared__ float gld[4 * 16 * 32]; // [gate][row][hid]

    const int tid = threadIdx.x;
    const int g = blockIdx.x >> 4;    // group (batch rows g*16..+15)
    const int s = blockIdx.x & 15;    // slice (hidden n0..n0+31)
    const int n0 = s * 32;
    const int w = tid >> 6;           // wave = gate index (0:i 1:j 2:f 3:o)
    const int l = tid & 63;
    const int l15 = l & 15, l4 = l >> 4;

    // stage Wh slice: gate cols {w*512+n0+hh}, k in [512,1024) of WT rows
    {
        const int cc = tid >> 1, hf = tid & 1;
        const int g4 = cc >> 5, hh = cc & 31;
        const size_t nglob = (size_t)g4 * 512 + n0 + hh;
        const uint4* src = (const uint4*)(WT + nglob * 1024 + 512 + hf * 256);
        uint4* dst = (uint4*)&WhT[cc * 520 + hf * 256];
        #pragma unroll
        for (int j = 0; j < 32; ++j) dst[j] = src[j];
    }
    // c state in registers (thread e owns (row=e>>5, hid=e&31), e = tid and tid+256)
    float c0 = cbuf[(size_t)(g * MG + (tid >> 5)) * 512 + n0 + (tid & 31)];
    float c1 = cbuf[(size_t)(g * MG + ((tid + 256) >> 5)) * 512 + n0 + (tid & 31)];
    const float bb0 = bias[w * 512 + n0 + l15];
    const float bb1 = bias[w * 512 + n0 + 16 + l15];
    __syncthreads();

    int* flags = arr + g * 512;

    for (int tl = 0; tl < TC; ++tl) {
        const int t = t0 + tl;
        // preload XW (independent of h -> overlaps the spin)
        const f16* xwp = XW + ((size_t)tl * 256 + g * MG) * 2048 + (size_t)w * 512 + n0;
        f16 xw0[4], xw1[4];
        #pragma unroll
        for (int rr = 0; rr < 4; ++rr) {
            int rd = l4 * 4 + rr;
            xw0[rr] = xwp[(size_t)rd * 2048 + l15];
            xw1[rr] = xwp[(size_t)rd * 2048 + 16 + l15];
        }
        // wait for h_t from all slices of the group (all threads: acquire)
        if (t > 0) {
            while (__hip_atomic_load(&flags[t - 1], __ATOMIC_ACQUIRE, __HIP_MEMORY_SCOPE_AGENT) < SS)
                __builtin_amdgcn_s_sleep(2);
        }
        // stage h_t [16][512] fp16
        {
            const int row = tid >> 4, seg = tid & 15;
            const uint4* src = (const uint4*)(hbuf + ((size_t)(g * 2 + (t & 1)) * MG + row) * 512 + seg * 32);
            uint4* dst = (uint4*)&hld[row * 520 + seg * 32];
            #pragma unroll
            for (int j = 0; j < 4; ++j) dst[j] = src[j];
        }
        __syncthreads();
        // gates slice = XW + bias + h @ Wh   (wave w: 2 subtiles x 16 MFMAs)
        f32x4 a0, a1;
        #pragma unroll
        for (int rr = 0; rr < 4; ++rr) { a0[rr] = (float)xw0[rr] + bb0; a1[rr] = (float)xw1[rr] + bb1; }
        const f16* ap = &hld[l15 * 520 + l4 * 8];
        const f16* bp0 = &WhT[(w * 32 + l15) * 520 + l4 * 8];
        const f16* bp1 = &WhT[(w * 32 + 16 + l15) * 520 + l4 * 8];
        #pragma unroll
        for (int ki = 0; ki < 16; ++ki) {
            f16x8 af = *(const f16x8*)(ap + ki * 32);
            f16x8 bf0 = *(const f16x8*)(bp0 + ki * 32);
            f16x8 bf1 = *(const f16x8*)(bp1 + ki * 32);
            a0 = __builtin_amdgcn_mfma_f32_16x16x32_f16(af, bf0, a0, 0, 0, 0);
            a1 = __builtin_amdgcn_mfma_f32_16x16x32_f16(af, bf1, a1, 0, 0, 0);
        }
        #pragma unroll
        for (int rr = 0; rr < 4; ++rr) {
            int rd = l4 * 4 + rr;
            gld[(w * 16 + rd) * 32 + l15] = a0[rr];
            gld[(w * 16 + rd) * 32 + 16 + l15] = a1[rr];
        }
        __syncthreads();
        // cell update: 512 elems / 256 threads
        {
            const int row = tid >> 5, hid = tid & 31;
            float gi = gld[(0 * 16 + row) * 32 + hid], gj = gld[(1 * 16 + row) * 32 + hid];
            float gf = gld[(2 * 16 + row) * 32 + hid], go = gld[(3 * 16 + row) * 32 + hid];
            float nc = c0 * sigf(gf + 1.0f) + sigf(gi) * tanh_(gj);
            float h = tanh_(nc) * sigf(go);
            c0 = nc;
            out[((size_t)(g * MG + row) * T_ + t) * H_ + n0 + hid] = h;
            hbuf[((size_t)(g * 2 + ((t + 1) & 1)) * MG + row) * 512 + n0 + hid] = (f16)h;

            const int row1 = row + 8;
            float gi1 = gld[(0 * 16 + row1) * 32 + hid], gj1 = gld[(1 * 16 + row1) * 32 + hid];
            float gf1 = gld[(2 * 16 + row1) * 32 + hid], go1 = gld[(3 * 16 + row1) * 32 + hid];
            float nc1 = c1 * sigf(gf1 + 1.0f) + sigf(gi1) * tanh_(gj1);
            float h1 = tanh_(nc1) * sigf(go1);
            c1 = nc1;
            out[((size_t)(g * MG + row1) * T_ + t) * H_ + n0 + hid] = h1;
            hbuf[((size_t)(g * 2 + ((t + 1) & 1)) * MG + row1) * 512 + n0 + hid] = (f16)h1;
        }
        __threadfence();
        __syncthreads();
        if (tid == 0)
            __hip_atomic_fetch_add(&flags[t], 1, __ATOMIC_RELEASE, __HIP_MEMORY_SCOPE_AGENT);
    }
    cbuf[(size_t)(g * MG + (tid >> 5)) * 512 + n0 + (tid & 31)] = c0;
    cbuf[(size_t)(g * MG + ((tid + 256) >> 5)) * 512 + n0 + (tid & 31)] = c1;
}

extern "C" void kernel_launch(void* const* d_in, const int* in_sizes, int n_in,
                              void* d_out, int out_size, void* d_ws, size_t ws_size,
                              hipStream_t stream) {
    (void)in_sizes; (void)n_in; (void)out_size;
    const float* x = (const float*)d_in[0];
    const float* W = (const float*)d_in[1];
    const float* bias = (const float*)d_in[2];
    float* out = (float*)d_out;
    char* ws = (char*)d_ws;

    // ws layout (bytes):
    //   WT   @ 0         : 2048*1024*2 = 4,194,304
    //   hbuf @ 4,194,304 : 16*2*16*512*2 = 524,288
    //   cbuf @ 4,718,592 : 256*512*4 = 524,288
    //   arr  @ 5,242,880 : 16*512*4 = 32,768
    //   x16  @ 5,275,648 : TC*256*512*2 = TC*262,144
    //   XW   @ x16+      : TC*256*2048*2 = TC*1,048,576
    int TC = 8;
    {
        const int cands[7] = {512, 256, 128, 64, 32, 16, 8};
        for (int i = 0; i < 7; ++i) {
            if (5275648ull + (unsigned long long)cands[i] * 1310720ull <= (unsigned long long)ws_size) {
                TC = cands[i];
                break;
            }
        }
    }
    f16* WT = (f16*)(ws);
    f16* hbuf = (f16*)(ws + 4194304);
    float* cbuf = (float*)(ws + 4718592);
    int* arr = (int*)(ws + 5242880);
    f16* x16 = (f16*)(ws + 5275648);
    f16* XW = (f16*)(ws + 5275648 + (size_t)TC * 262144);

    // zero h0 / c0 / arrive counters (ws is poisoned 0xAA before every call)
    hipMemsetAsync(ws + 4194304, 0, 1081344, stream);
    prep_w<<<dim3(1024), dim3(256), 0, stream>>>(W, WT);

    const int nch = T_ / TC;
    for (int c = 0; c < nch; ++c) {
        const int t0 = c * TC;
        prep_x<<<dim3(256, TC), dim3(64), 0, stream>>>(x, x16, t0);
        xw_gemm<<<dim3(16, TC * 2), dim3(256), 0, stream>>>(x16, WT, XW);
        rnn_chunk<<<dim3(256), dim3(256), 0, stream>>>(XW, WT, bias, hbuf, cbuf, arr, out, t0, TC);
    }
}